// Round 11
// baseline (124.102 us; speedup 1.0000x reference)
//
#include <hip/hip_runtime.h>
#include <stdint.h>

// SimCLR loss, B=4096, D=512, TAU=0.1.  out[0]=loss, out[1]=acc(%).
//
// Round 11: round-10 MX structure with BOTH views resident (register-feasible
// now because MX acc is 16 regs/view at 32-col tiles): single pass over 16
// 32-col tiles, each staged B-operand feeds both a-left and b-left MFMAs.
// vs round 10: LDS reads halve (256/wave), staged bytes halve (256KB/block),
// barrier-drain volume halves; MFMA+epilogue unchanged. Est ~250 VGPRs --
// spill tell is WRITE_SIZE (round-4 lesson).
// Fixed-max softmax (logits bounded by 10) -> additive partials, plain
// per-split stores. Label logit exact fp32 (prep); diag masked in-kernel.

#define BN 4096
#define DK 512            // K elements = bytes per row in fp8
#define NSPLIT 16
#define NEG_BIG -1e30f
#define SCL 0.15625f      // 1/(8*8*TAU)
#define SCL2 0.225396744f // SCL * log2(e)
#define C2 14.4269504f    // 10 * log2(e)
#define TILE_BYTES (32 * DK)  // 16 KB per 32-col fp8 tile

typedef __attribute__((ext_vector_type(16))) float floatx16;
typedef __attribute__((ext_vector_type(8))) int intx8;

// ---------------- prep: normalize, fp8-pack (K-permuted), label, zero -----
// Permuted layout: byte position kc2*32 + h*16 + t*8 + j holds original
// k = kc2*32 + t*16 + h*8 + j.  16B chunk (kc2,h) = K=16-sub-block operand
// bytes; chunks (2i,h),(2i+1,h) concatenated = one K=64 MX operand half.
__global__ void __launch_bounds__(256) prep_kernel(
    const float* __restrict__ A, const float* __restrict__ Bv,
    unsigned char* __restrict__ An, unsigned char* __restrict__ Bn,
    float* __restrict__ diag, float* __restrict__ out) {
  if (blockIdx.x == 0 && threadIdx.x < 2) out[threadIdx.x] = 0.0f;
  const int w = threadIdx.x >> 6, lane = threadIdx.x & 63;
  const int row = blockIdx.x * 4 + w;
  const float4* pa4 = (const float4*)(A + (size_t)row * DK);
  const float4* pb4 = (const float4*)(Bv + (size_t)row * DK);
  float4 a0 = pa4[lane * 2], a1 = pa4[lane * 2 + 1];  // k = lane*8 .. +7
  float4 b0 = pb4[lane * 2], b1 = pb4[lane * 2 + 1];
  float ssa = a0.x * a0.x + a0.y * a0.y + a0.z * a0.z + a0.w * a0.w +
              a1.x * a1.x + a1.y * a1.y + a1.z * a1.z + a1.w * a1.w;
  float ssb = b0.x * b0.x + b0.y * b0.y + b0.z * b0.z + b0.w * b0.w +
              b1.x * b1.x + b1.y * b1.y + b1.z * b1.z + b1.w * b1.w;
  float sab = a0.x * b0.x + a0.y * b0.y + a0.z * b0.z + a0.w * b0.w +
              a1.x * b1.x + a1.y * b1.y + a1.z * b1.z + a1.w * b1.w;
#pragma unroll
  for (int off = 32; off > 0; off >>= 1) {
    ssa += __shfl_xor(ssa, off);
    ssb += __shfl_xor(ssb, off);
    sab += __shfl_xor(sab, off);
  }
  float na = fmaxf(sqrtf(ssa), 1e-12f);
  float nb = fmaxf(sqrtf(ssb), 1e-12f);
  const float s = 8.0f;  // fp8 pre-scale: keeps elems mid-range in e4m3
  float sa = s / na, sb = s / nb;
  const int doff = (lane >> 2) * 32 + (lane & 1) * 16 + ((lane >> 1) & 1) * 8;
  {
    int v0 = __builtin_amdgcn_cvt_pk_fp8_f32(a0.x * sa, a0.y * sa, 0, false);
    v0 = __builtin_amdgcn_cvt_pk_fp8_f32(a0.z * sa, a0.w * sa, v0, true);
    int v1 = __builtin_amdgcn_cvt_pk_fp8_f32(a1.x * sa, a1.y * sa, 0, false);
    v1 = __builtin_amdgcn_cvt_pk_fp8_f32(a1.z * sa, a1.w * sa, v1, true);
    int2 pv; pv.x = v0; pv.y = v1;
    *(int2*)(An + (size_t)row * DK + doff) = pv;
  }
  {
    int v0 = __builtin_amdgcn_cvt_pk_fp8_f32(b0.x * sb, b0.y * sb, 0, false);
    v0 = __builtin_amdgcn_cvt_pk_fp8_f32(b0.z * sb, b0.w * sb, v0, true);
    int v1 = __builtin_amdgcn_cvt_pk_fp8_f32(b1.x * sb, b1.y * sb, 0, false);
    v1 = __builtin_amdgcn_cvt_pk_fp8_f32(b1.z * sb, b1.w * sb, v1, true);
    int2 pv; pv.x = v0; pv.y = v1;
    *(int2*)(Bn + (size_t)row * DK + doff) = pv;
  }
  if (lane == 0) diag[row] = (sab / (na * nb)) * 10.0f;  // exact fp32 /TAU
}

// ---------------- tiles: MX fp8 MFMA, both views, single pass, dbuf -------
// grid = (32 row-blocks, 16 col-splits) = 512 blocks = 2/CU. 4 waves/block,
// wave owns 32 rows; a-left AND b-left fragments resident. 256 unified
// 32-col tiles; split owns 16. Each staged tile feeds both problems.
__global__ void __launch_bounds__(256, 2) tiles_kernel(
    const unsigned char* __restrict__ An, const unsigned char* __restrict__ Bn,
    float* __restrict__ pSA, float* __restrict__ pMA, float* __restrict__ pSB) {
  __shared__ __align__(16) unsigned char smem[2 * TILE_BYTES];  // 32 KB

  const int rb = blockIdx.x;     // 0..31 (128-row panel)
  const int split = blockIdx.y;  // 0..15 (16 j-tiles of 32 cols each)
  const int tid = threadIdx.x;
  const int lane = tid & 63, w = tid >> 6;
  const int n5 = lane & 31, h = lane >> 5;
  const int r0 = rb * 128;
  const int myrow = r0 + w * 32 + n5;

  // both views' left K=64 MX operands: aw[i] = chunks (2i,h)||(2i+1,h)
  intx8 awA[8], awB[8];
  {
    const unsigned char* pA = An + (size_t)myrow * DK + h * 16;
    const unsigned char* pB = Bn + (size_t)myrow * DK + h * 16;
#pragma unroll
    for (int i = 0; i < 8; ++i) {
      int4 c0 = *(const int4*)(pA + i * 64);
      int4 c1 = *(const int4*)(pA + i * 64 + 32);
      intx8 v = {c0.x, c0.y, c0.z, c0.w, c1.x, c1.y, c1.z, c1.w};
      awA[i] = v;
      c0 = *(const int4*)(pB + i * 64);
      c1 = *(const int4*)(pB + i * 64 + 32);
      intx8 u = {c0.x, c0.y, c0.z, c0.w, c1.x, c1.y, c1.z, c1.w};
      awB[i] = u;
    }
  }

  // fixed-max state: l = sum exp(logit-10) per problem; mx = full_a max acc
  float lA[16], lB[16], mx[16];
#pragma unroll
  for (int r = 0; r < 16; ++r) { lA[r] = 0.f; lB[r] = 0.f; mx[r] = NEG_BIG; }

  // stage a 32-col fp8 tile (16 KB); one inst = 2 cols (h=0 even, h=1 odd).
  // XOR swizzle: physical 16B chunk p of col c holds logical chunk p^(c&7).
  auto stage = [&](unsigned char* buf, int jt) {
    const unsigned char* csrc = (jt < 128) ? An : Bn;
    const int cb = (jt & 127) * 32;
#pragma unroll
    for (int ii = 0; ii < 4; ++ii) {  // wave w: colpairs w*4 .. w*4+3
      const int cp = w * 4 + ii;
      const int cl = cp * 2 + h;
      const unsigned char* src =
          csrc + (size_t)(cb + cl) * DK + ((n5 ^ (cl & 7)) * 16);
      __builtin_amdgcn_global_load_lds(
          (const __attribute__((address_space(1))) void*)src,
          (__attribute__((address_space(3))) void*)(buf + cp * 1024),
          16, 0, 0);
    }
  };

  stage(smem, split * 16);
  __syncthreads();

  const int swz = n5 & 7;
  for (int u = 0; u < 16; ++u) {
    const int jt = split * 16 + u;
    unsigned char* cur = smem + (u & 1) * TILE_BYTES;
    unsigned char* nxt = smem + ((u + 1) & 1) * TILE_BYTES;
    if (u < 15) stage(nxt, jt + 1);  // prefetch; drained at this iter's barrier

    floatx16 accA, accB;
#pragma unroll
    for (int r = 0; r < 16; ++r) { accA[r] = 0.f; accB[r] = 0.f; }

    // B K=64 operand: logical chunks (4i+h),(4i+2+h) of col n5; one operand
    // feeds BOTH views' MFMAs (the LDS-economy core of this round).
    const unsigned char* bbase = cur + (size_t)n5 * DK;
#pragma unroll
    for (int i = 0; i < 8; ++i) {
      const int p1 = ((4 * i + h) ^ swz) * 16;
      const int p2 = ((4 * i + 2 + h) ^ swz) * 16;
      int4 b0 = *(const int4*)(bbase + p1);
      int4 b1 = *(const int4*)(bbase + p2);
      intx8 bw = {b0.x, b0.y, b0.z, b0.w, b1.x, b1.y, b1.z, b1.w};
      accA = __builtin_amdgcn_mfma_scale_f32_32x32x64_f8f6f4(
          awA[i], bw, accA, 0, 0, 0, 0x7F7F7F7F, 0, 0x7F7F7F7F);
      accB = __builtin_amdgcn_mfma_scale_f32_32x32x64_f8f6f4(
          awB[i], bw, accB, 0, 0, 0, 0x7F7F7F7F, 0, 0x7F7F7F7F);
    }

    // epilogue: mask (i,i) of this half for BOTH problems (aa/bb masked diag
    // AND ab/ba label — label re-added exactly in finalize), exp-sum at
    // fixed max 10; mx (full_a accuracy) from masked accA only.
    const bool dtile = (((jt & 127) >> 2) == rb);
    const int colbase = (jt & 127) * 32;
#pragma unroll
    for (int r = 0; r < 16; ++r) {
      float vA = accA[r], vB = accB[r];
      if (dtile) {
        const int rowg = r0 + w * 32 + (r & 3) + 8 * (r >> 2) + 4 * h;
        if (rowg == colbase + n5) { vA = NEG_BIG; vB = NEG_BIG; }
      }
      mx[r] = fmaxf(mx[r], vA);
      lA[r] += exp2f(fmaf(vA, SCL2, -C2));
      lB[r] += exp2f(fmaf(vB, SCL2, -C2));
    }
    __syncthreads();  // cur consumed by all; nxt's DMA drained
  }

  // merge across the 32 n5-lanes (cols), emit per-split partials
#pragma unroll
  for (int off = 1; off < 32; off <<= 1)
#pragma unroll
    for (int r = 0; r < 16; ++r) {
      lA[r] += __shfl_xor(lA[r], off);
      lB[r] += __shfl_xor(lB[r], off);
      mx[r] = fmaxf(mx[r], __shfl_xor(mx[r], off));
    }
  if (n5 == 0) {
#pragma unroll
    for (int r = 0; r < 16; ++r) {
      const int row = r0 + w * 32 + (r & 3) + 8 * (r >> 2) + 4 * h;
      pSA[split * BN + row] = lA[r];
      pMA[split * BN + row] = mx[r] * SCL;  // logit-domain max
      pSB[split * BN + row] = lB[r];
    }
  }
}

// ---------------- finalize: merge 16 splits, add label, reduce ------------
__global__ void __launch_bounds__(256) finalize_kernel(
    const float* __restrict__ pSA, const float* __restrict__ pMA,
    const float* __restrict__ pSB, const float* __restrict__ diag,
    float* __restrict__ out) {
  const int row = blockIdx.x * 256 + threadIdx.x;
  float SA = 0.f, SB = 0.f, MA = NEG_BIG;
#pragma unroll
  for (int s = 0; s < NSPLIT; ++s) {
    SA += pSA[s * BN + row];
    SB += pSB[s * BN + row];
    MA = fmaxf(MA, pMA[s * BN + row]);
  }
  const float d = diag[row];
  const float eL = exp2f(fmaf(d, 1.44269504f, -C2));  // exp(d-10)
  float lseA = 10.0f + logf(SA + eL);
  float lseB = 10.0f + logf(SB + eL);
  float lossi = (lseA - d) + (lseB - d);
  float corr = (d >= MA) ? 1.f : 0.f;  // argmax(full_a)==label
#pragma unroll
  for (int off = 32; off > 0; off >>= 1) {
    lossi += __shfl_xor(lossi, off);
    corr += __shfl_xor(corr, off);
  }
  __shared__ float sred[2][4];
  if ((threadIdx.x & 63) == 0) {
    int w = threadIdx.x >> 6;
    sred[0][w] = lossi; sred[1][w] = corr;
  }
  __syncthreads();
  if (threadIdx.x == 0) {
    float ls = sred[0][0] + sred[0][1] + sred[0][2] + sred[0][3];
    float cs = sred[1][0] + sred[1][1] + sred[1][2] + sred[1][3];
    atomicAdd(&out[0], ls * (1.0f / 8192.0f));    // mean over rows, /2
    atomicAdd(&out[1], cs * (100.0f / 4096.0f));  // accuracy %
  }
}

extern "C" void kernel_launch(void* const* d_in, const int* in_sizes, int n_in,
                              void* d_out, int out_size, void* d_ws, size_t ws_size,
                              hipStream_t stream) {
  const float* A = (const float*)d_in[0];
  const float* Bv = (const float*)d_in[1];
  unsigned char* An = (unsigned char*)d_ws;                   // 4096x512 fp8
  unsigned char* Bn = An + (size_t)BN * DK;                   // 4096x512 fp8
  float* diag = (float*)(Bn + (size_t)BN * DK);               // 4096 f32
  float* pSA = diag + BN;                                     // [16][4096] f32
  float* pMA = pSA + NSPLIT * BN;                             // [16][4096] f32
  float* pSB = pMA + NSPLIT * BN;                             // [16][4096] f32
  float* out = (float*)d_out;

  prep_kernel<<<BN / 4, 256, 0, stream>>>(A, Bv, An, Bn, diag, out);
  tiles_kernel<<<dim3(32, 16), 256, 0, stream>>>(An, Bn, pSA, pMA, pSB);
  finalize_kernel<<<BN / 256, 256, 0, stream>>>(pSA, pMA, pSB, diag, out);
}